// Round 8
// baseline (416.863 us; speedup 1.0000x reference)
//
#include <hip/hip_runtime.h>
#include <math.h>

#define NS 4096
#define CH 512
#define EPSV 1e-5f

typedef __attribute__((ext_vector_type(8))) _Float16 f16x8;  // 8 x fp16 MFMA operand
typedef __attribute__((ext_vector_type(4))) float f32x4;     // MFMA accumulator
typedef unsigned short u16;

// ---------- fp16 helpers (RNE via cast) ----------
__device__ __forceinline__ u16 f2h(float x) {
    _Float16 h = (_Float16)x;
    return __builtin_bit_cast(unsigned short, h);
}
__device__ __forceinline__ float h2f(u16 b) {
    return (float)__builtin_bit_cast(_Float16, b);
}

// ---------- async global->LDS, 16B per lane ----------
__device__ __forceinline__ void gload16(const void* g, void* l) {
    __builtin_amdgcn_global_load_lds((const __attribute__((address_space(1))) unsigned*)g,
                                     (__attribute__((address_space(3))) unsigned*)l, 16, 0, 0);
}

// per-z dispatch table. np[z] = number of operand planes staged (prefix of
// [Ahi, Bhi, Alo, Blo]):
//   np=2 -> out = Ahi*Bhi            (1 MFMA term)
//   np=3 -> out = (Ahi+Alo)*Bhi      (2 terms)
//   np=4 -> out = (Ahi+Alo)*Bhi + Ahi*Blo   (3 terms; ll ~2^-22 dropped)
// mode: 0 = fp32 out (+bias, +resid), 1 = packed fp16 HI-ONLY out [K/8][N][8].
struct ZTab {
    long aoff[6];
    long boff[6];
    long ooff[6];
    int  mode[6];
    int  np[6];
    const float* bias[6];
};

// =====================================================================================
// Split-fp16 GEMM:  out[m][n] = sum_k A[k][m] * B[k][n]
// Packed operand layout: element (k, x) at ((k>>3)*W + x)*8 + (k&7)
// Tile 128x128, BK=32, 4 waves (2x2), per-wave 64x64 via 4x4 frags of 16x16x32.
// 2-phase double-buffered pipeline. NP = max planes (LDS sizing); tab.np[z] <= NP.
// COLST: epilogue emits per-column softmax partials (max, sum(exp)) per 64-row group.
// =====================================================================================
template<int NP, bool RESID, bool COLST>
__global__ __launch_bounds__(256, (NP == 2 ? 4 : (NP == 3 ? 3 : 2))) void gemm_split(
    const u16* __restrict__ Ahi, const u16* __restrict__ Alo,
    const u16* __restrict__ Bhi, const u16* __restrict__ Blo,
    const float* __restrict__ resid,
    float* __restrict__ outF, u16* __restrict__ outH,
    float* __restrict__ pmg, float* __restrict__ psg,
    int Mw, int Nw, int K, ZTab tab)
{
    __shared__ u16 smem[2][NP * 4 * 128 * 8];   // 2 x (NP*8KB) double buffer
    const int t = threadIdx.x;
    const int lane = t & 63;
    const int wid = t >> 6;
    const int wm = wid >> 1, wn = wid & 1;
    const int lk = lane >> 4, lm = lane & 15;
    const int m0 = blockIdx.y * 128, n0 = blockIdx.x * 128;
    const int z = blockIdx.z;
    const int npz = tab.np[z];
    const u16* pAhi = Ahi + tab.aoff[z];
    const u16* pAlo = Alo + tab.aoff[z];
    const u16* pBhi = Bhi + tab.boff[z];
    const u16* pBlo = (NP == 4) ? (Blo + tab.boff[z]) : nullptr;

    f32x4 acc[4][4] = {};

    // stage K-tile ks into LDS buffer buf; planes 0..npz-1, prefix [Ahi,Bhi,Alo,Blo]
    auto stage = [&](int buf, int ks) {
        const int kp0 = ks << 2;
        for (int i = 0; i < 2 * npz; ++i) {
            const int q = i * 4 + wid;                 // wave-uniform
            const int b = q >> 3;                      // plane id
            const int p = (q & 7) >> 1;                // k-plane
            const int w = ((q & 1) << 6) + lane;       // width index 0..127
            const u16* src;
            if (b == 0)      src = pAhi + ((size_t)(kp0 + p) * Mw + m0 + w) * 8;
            else if (b == 1) src = pBhi + ((size_t)(kp0 + p) * Nw + n0 + w) * 8;
            else if (b == 2) src = pAlo + ((size_t)(kp0 + p) * Mw + m0 + w) * 8;
            else             src = pBlo + ((size_t)(kp0 + p) * Nw + n0 + w) * 8;
            gload16(src, &smem[buf][(size_t)(((b * 4 + p) * 128) + w) * 8]);
        }
    };

    const int nK = K >> 5;
    stage(0, 0);
    __syncthreads();                 // drains vmcnt(0): buf0 ready
    int cur = 0;
    for (int ks = 0; ks < nK; ++ks) {
        if (ks + 1 < nK) stage(cur ^ 1, ks + 1);   // prefetch next tile during MFMA
        const u16* sm = smem[cur];
        f16x8 ah[4], al[4], bh[4], bl[4];
        #pragma unroll
        for (int f = 0; f < 4; ++f) {
            ah[f] = *(const f16x8*)&sm[((0 * 4 + lk) * 128 + wm * 64 + f * 16 + lm) * 8];
            bh[f] = *(const f16x8*)&sm[((1 * 4 + lk) * 128 + wn * 64 + f * 16 + lm) * 8];
        }
        if (NP >= 3 && npz >= 3)
            #pragma unroll
            for (int f = 0; f < 4; ++f)
                al[f] = *(const f16x8*)&sm[((2 * 4 + lk) * 128 + wm * 64 + f * 16 + lm) * 8];
        if (NP == 4 && npz >= 4)
            #pragma unroll
            for (int f = 0; f < 4; ++f)
                bl[f] = *(const f16x8*)&sm[((3 * 4 + lk) * 128 + wn * 64 + f * 16 + lm) * 8];
        #pragma unroll
        for (int i = 0; i < 4; ++i)
            #pragma unroll
            for (int j = 0; j < 4; ++j)
                acc[i][j] = __builtin_amdgcn_mfma_f32_16x16x32_f16(ah[i], bh[j], acc[i][j], 0, 0, 0);
        if (NP >= 3 && npz >= 3)
            #pragma unroll
            for (int i = 0; i < 4; ++i)
                #pragma unroll
                for (int j = 0; j < 4; ++j)
                    acc[i][j] = __builtin_amdgcn_mfma_f32_16x16x32_f16(al[i], bh[j], acc[i][j], 0, 0, 0);
        if (NP == 4 && npz >= 4)
            #pragma unroll
            for (int i = 0; i < 4; ++i)
                #pragma unroll
                for (int j = 0; j < 4; ++j)
                    acc[i][j] = __builtin_amdgcn_mfma_f32_16x16x32_f16(ah[i], bl[j], acc[i][j], 0, 0, 0);
        __syncthreads();             // prefetched buffer complete, reads done
        cur ^= 1;
    }
    // ---- epilogue: C/D layout col = lane&15, row = (lane>>4)*4 + reg ----
    const float* bp = tab.bias[z];
    if (tab.mode[z] == 0) {
        float* pout = outF + tab.ooff[z];
        #pragma unroll
        for (int i = 0; i < 4; ++i) {
            #pragma unroll
            for (int r = 0; r < 4; ++r) {
                const int m = m0 + wm * 64 + i * 16 + lk * 4 + r;
                const float bv = bp ? bp[m] : 0.f;
                const size_t ro = (size_t)m * Nw + n0 + wn * 64 + lm;
                #pragma unroll
                for (int j = 0; j < 4; ++j) {
                    float v = acc[i][j][r] + bv;
                    if (RESID) v += resid[tab.ooff[z] + ro + j * 16];
                    pout[ro + j * 16] = v;
                }
            }
        }
    } else {
        // packed fp16 hi-only out: element (k=m, x=n) -> ((m>>3)*Nw + n)*8 + (m&7)
        u16* ph = outH + tab.ooff[z];
        #pragma unroll
        for (int i = 0; i < 4; ++i) {
            float bv[4];
            #pragma unroll
            for (int r = 0; r < 4; ++r) {
                const int m = m0 + wm * 64 + i * 16 + lk * 4 + r;
                bv[r] = bp ? bp[m] : 0.f;
            }
            const long rg = (long)((m0 + wm * 64) >> 3) + i * 2 + (lk >> 1);
            const int sub = (lk & 1) * 4;
            #pragma unroll
            for (int j = 0; j < 4; ++j) {
                const int n = n0 + wn * 64 + j * 16 + lm;
                const long idx = (rg * Nw + n) * 8 + sub;
                u16 h[4];
                #pragma unroll
                for (int r = 0; r < 4; ++r)
                    h[r] = f2h(acc[i][j][r] + bv[r]);
                *(ushort4*)&ph[idx] = make_ushort4(h[0], h[1], h[2], h[3]);
            }
        }
    }
    if (COLST) {
        // per-column partial softmax stats over this wave-row's 64 s-rows.
        #pragma unroll
        for (int j = 0; j < 4; ++j) {
            float mx = -3.0e38f;
            #pragma unroll
            for (int i = 0; i < 4; ++i)
                #pragma unroll
                for (int r = 0; r < 4; ++r)
                    mx = fmaxf(mx, acc[i][j][r]);
            mx = fmaxf(mx, __shfl_xor(mx, 16));
            mx = fmaxf(mx, __shfl_xor(mx, 32));
            float sum = 0.f;
            #pragma unroll
            for (int i = 0; i < 4; ++i)
                #pragma unroll
                for (int r = 0; r < 4; ++r)
                    sum += __expf(acc[i][j][r] - mx);
            sum += __shfl_xor(sum, 16);
            sum += __shfl_xor(sum, 32);
            if (lk == 0) {
                const int n = n0 + wn * 64 + j * 16 + lm;
                const int grp = (m0 >> 6) + wm;          // 64 row-groups
                pmg[(size_t)grp * NS + n] = mx;
                psg[(size_t)grp * NS + n] = sum;
            }
        }
    }
}

// =====================================================================================
// packB: fp32 [K][N] (batched) -> fp16 hi(/lo) packed [K/8][N][8]. Optional fused exp.
// grid: (N/256, K/8, batches)
// =====================================================================================
template<bool EXPSC, bool WLO>
__global__ __launch_bounds__(256) void packB_k(const float* __restrict__ X,
    u16* __restrict__ Hi, u16* __restrict__ Lo,
    const float* __restrict__ mx, const float* __restrict__ inv,
    int Nw, long xB, long pB)
{
    const int n = blockIdx.x * 256 + threadIdx.x;
    const int p = blockIdx.y;
    const int z = blockIdx.z;
    const float* Xp = X + (size_t)z * xB + ((size_t)p * 8) * Nw + n;
    float em = 0.f, ei = 1.f;
    if (EXPSC) { em = mx[n]; ei = inv[n]; }
    u16 hi[8], lo[8];
    #pragma unroll
    for (int j = 0; j < 8; ++j) {
        float v = Xp[(size_t)j * Nw];
        if (EXPSC) v = __expf(v - em) * ei;
        u16 h = f2h(v);
        hi[j] = h;
        if (WLO) lo[j] = f2h(v - h2f(h));
    }
    const size_t o = (size_t)z * pB + ((size_t)p * Nw + n) * 8;
    *(uint4*)&Hi[o] = *(const uint4*)hi;
    if (WLO) *(uint4*)&Lo[o] = *(const uint4*)lo;
}

// =====================================================================================
// packA_T: weight W [M=512][K] fp32 -> transposed packed [K/8][512][8] hi/lo
// grid: (K/64, 512/64)
// =====================================================================================
__global__ __launch_bounds__(256) void packA_T(const float* __restrict__ W,
    u16* __restrict__ Hi, u16* __restrict__ Lo, int Kdim)
{
    __shared__ float tile[64][65];
    const int t = threadIdx.x;
    const int k0 = blockIdx.x * 64, m0 = blockIdx.y * 64;
    const int kk = t & 63, mb = t >> 6;
    #pragma unroll
    for (int it = 0; it < 16; ++it) {
        int mm = mb + it * 4;
        tile[mm][kk] = W[(size_t)(m0 + mm) * Kdim + k0 + kk];
    }
    __syncthreads();
    #pragma unroll
    for (int cc = 0; cc < 2; ++cc) {
        int c = t + cc * 256;
        int kp = c >> 6, m = c & 63;
        u16 hi[8], lo[8];
        #pragma unroll
        for (int j = 0; j < 8; ++j) {
            float v = tile[m][kp * 8 + j];
            u16 h = f2h(v);
            hi[j] = h;
            lo[j] = f2h(v - h2f(h));
        }
        size_t o = ((size_t)(k0 / 8 + kp) * CH + m0 + m) * 8;
        *(uint4*)&Hi[o] = *(const uint4*)hi;
        *(uint4*)&Lo[o] = *(const uint4*)lo;
    }
}

// =====================================================================================
// pack_hvT (quantized-moments form): Hv fp32 [C][N] ->
//   H1h = fp16(hv)                                  (Mean A-plane, 1 term)
//   H2h/H2l = hi/lo split of (fp16(hv))^2 (exact)   (Sec A-planes, 2 terms)
// Mean/Sec then are EXACT moments of the quantized hv -> Var >= 0 structurally;
// dstd <= 2^-11 * RMS(hv) by Cauchy-Schwarz.
// grid: (N/64, C/64, 2=batch)
// =====================================================================================
__global__ __launch_bounds__(256) void pack_hvT(const float* __restrict__ Hv,
    u16* __restrict__ H1h, u16* __restrict__ H2h, u16* __restrict__ H2l)
{
    __shared__ float tile[64][65];
    const int t = threadIdx.x;
    const int s0 = blockIdx.x * 64, c0 = blockIdx.y * 64;
    const int z = blockIdx.z;
    const float* src = Hv + (size_t)z * CH * NS;
    const int ss = t & 63, cb = t >> 6;
    #pragma unroll
    for (int it = 0; it < 16; ++it) {
        int cc = cb + it * 4;
        tile[cc][ss] = src[(size_t)(c0 + cc) * NS + s0 + ss];
    }
    __syncthreads();
    const size_t zb = (size_t)z * NS * CH;
    #pragma unroll
    for (int cc2 = 0; cc2 < 2; ++cc2) {
        int c = t + cc2 * 256;
        int sp = c >> 6, cm = c & 63;
        u16 h1[8], h2[8], l2[8];
        #pragma unroll
        for (int j = 0; j < 8; ++j) {
            float v = tile[cm][sp * 8 + j];
            u16 a = f2h(v);
            h1[j] = a;
            float q = h2f(a);
            float q2 = q * q;              // <=22-bit mantissa: exact in fp32
            u16 b = f2h(q2);
            h2[j] = b;
            l2[j] = f2h(q2 - h2f(b));
        }
        size_t o = zb + ((size_t)(s0 / 8 + sp) * CH + c0 + cm) * 8;
        *(uint4*)&H1h[o] = *(const uint4*)h1;
        *(uint4*)&H2h[o] = *(const uint4*)h2;
        *(uint4*)&H2l[o] = *(const uint4*)l2;
    }
}

// =====================================================================================
// colstats_comb64: combine 64 row-group partials -> column max + 1/sum
// =====================================================================================
__global__ __launch_bounds__(256) void colstats_comb64(const float* __restrict__ pm,
    const float* __restrict__ ps, float* __restrict__ mx, float* __restrict__ inv)
{
    const int n = blockIdx.x * 256 + threadIdx.x;
    float m = -3.0e38f, s = 0.f;
    #pragma unroll 8
    for (int g = 0; g < 64; ++g) {
        float gm = pm[(size_t)g * NS + n], gs = ps[(size_t)g * NS + n];
        float nm = fmaxf(m, gm);
        s = s * __expf(m - nm) + gs * __expf(gm - nm);
        m = nm;
    }
    mx[n] = m;
    inv[n] = 1.f / s;
}

// ================= per-(b,c) content stats =================
__global__ __launch_bounds__(256) void content_stats(const float* __restrict__ content,
                                                     float* __restrict__ cmean,
                                                     float* __restrict__ cinv)
{
    const int bc = blockIdx.x;
    const float4* p = (const float4*)(content + (size_t)bc * NS);
    const int t = threadIdx.x;
    float s = 0.f, s2 = 0.f;
    #pragma unroll
    for (int j = 0; j < 4; ++j) {
        float4 v = p[t + j * 256];
        s  += (v.x + v.y) + (v.z + v.w);
        s2 += (v.x * v.x + v.y * v.y) + (v.z * v.z + v.w * v.w);
    }
    #pragma unroll
    for (int off = 32; off >= 1; off >>= 1) {
        s  += __shfl_xor(s, off);
        s2 += __shfl_xor(s2, off);
    }
    __shared__ float r1[4], r2[4];
    const int wid = t >> 6;
    if ((t & 63) == 0) { r1[wid] = s; r2[wid] = s2; }
    __syncthreads();
    if (t == 0) {
        s  = (r1[0] + r1[1]) + (r1[2] + r1[3]);
        s2 = (r2[0] + r2[1]) + (r2[2] + r2[3]);
        const float mean = s * (1.0f / 4096.f);
        const float var = (s2 - 4096.f * mean * mean) * (1.0f / 4095.f);
        cmean[bc] = mean;
        cinv[bc] = rsqrtf(fmaxf(var, 0.f) + EPSV);
    }
}

// =====================================================================================
// compute_O + fused O-pack (hi only): O = sqrt(max(Sec-Mean^2,0))*norm(content)+Mean,
// written packed fp16 [C/8][NS][8] per batch. grid: (NS/256, CH/8, 2)
// =====================================================================================
__global__ __launch_bounds__(256) void compute_O_pack(
    const float* __restrict__ Mean, const float* __restrict__ Sec,
    const float* __restrict__ content,
    const float* __restrict__ cmean, const float* __restrict__ cinv,
    u16* __restrict__ Oh)
{
    const int n  = blockIdx.x * 256 + threadIdx.x;
    const int cg = blockIdx.y;
    const int b  = blockIdx.z;
    const size_t KN = (size_t)CH * NS;
    u16 h[8];
    #pragma unroll
    for (int j = 0; j < 8; ++j) {
        const int c = cg * 8 + j;
        const size_t po = (size_t)b * KN + (size_t)c * NS + n;
        const float mn = Mean[po];
        const float sc = Sec[po];
        const float ct = content[po];
        const int bc = b * CH + c;
        const float o = sqrtf(fmaxf(sc - mn * mn, 0.f)) * ((ct - cmean[bc]) * cinv[bc]) + mn;
        h[j] = f2h(o);
    }
    const size_t off = (size_t)b * KN + ((size_t)cg * NS + n) * 8;
    *(uint4*)&Oh[off] = *(const uint4*)h;
}

// =====================================================================================
extern "C" void kernel_launch(void* const* d_in, const int* in_sizes, int n_in,
                              void* d_out, int out_size, void* d_ws, size_t ws_size,
                              hipStream_t stream)
{
    const float* content = (const float*)d_in[0];
    const float* style   = (const float*)d_in[1];
    const float* f_w   = (const float*)d_in[2];
    const float* f_b   = (const float*)d_in[3];
    const float* g_w   = (const float*)d_in[4];
    const float* g_b   = (const float*)d_in[5];
    const float* h_w   = (const float*)d_in[6];
    const float* h_b   = (const float*)d_in[7];
    const float* out_w = (const float*)d_in[8];
    const float* out_b = (const float*)d_in[9];
    float* out = (float*)d_out;

    char* ws = (char*)d_ws;
    size_t off = 0;
    auto alloc = [&](size_t bytes) -> void* {
        void* p = ws + off;
        off = (off + bytes + 255) & ~(size_t)255;
        return p;
    };

    const size_t KN   = (size_t)CH * NS;      // 2,097,152 elements (one batch plane)
    const size_t CHCH = (size_t)CH * CH;
    const long   NSNS = (long)NS * NS;

    // ---- weight packs: contiguous [Wh0 Wl0 Wh1 Wl1 Wh2 Wl2 Wh3 Wl3] ----
    u16 *Wh[4], *Wl[4];
    for (int w = 0; w < 4; ++w) { Wh[w] = (u16*)alloc(CHCH * 2); Wl[w] = (u16*)alloc(CHCH * 2); }

    // ---- R2: one 8*KN u16 region, two time-disjoint layouts:
    //   phase 1 (conv inputs):  [Xc_hi | Xc_lo | Xs_hi | Xs_lo]        (each 2KN)
    //   phase 2 (PV A-packs):   [HvT_hi | Hv2T_hi | Hv2T_lo]          (each 2KN)
    u16* R2 = (u16*)alloc(8 * KN * 2);
    u16* Xc_hi = R2;            u16* Xc_lo = R2 + 2 * KN;
    u16* Xs_hi = R2 + 4 * KN;   u16* Xs_lo = R2 + 6 * KN;
    u16* HvT_hi  = R2;                // Mean A-plane (1 term)
    u16* Hv2T_hi = R2 + 2 * KN;       // Sec A-hi
    u16* Hv2T_lo = R2 + 4 * KN;       // Sec A-lo

    // ---- R3: [Fqp_hi | Gkp_hi], each 2KN u16 (hi-only); Gkp reused as O pack ----
    u16* Fqp_hi = (u16*)alloc(2 * KN * 2);
    u16* Gkp_hi = (u16*)alloc(2 * KN * 2);
    u16* Op_hi  = Gkp_hi;

    // ---- R4: P packs (hi only), BOTH batches for merged PV ----
    u16* Pp = (u16*)alloc(2 * (size_t)NS * NS * 2);

    // ---- R5: fp32 union: Hv32 -> S32 (67.2 MB) ----
    char* R5 = (char*)alloc((size_t)NS * NS * 4);
    float* Hv32 = (float*)(R5 + 4 * KN * 4);   // conv z=4,5 output (dead after pack_hvT)
    float* S32  = (float*)R5;

    // ---- R6: Mean/Sec fp32, contiguous (Sec32 = Mean32 + 2KN floats) ----
    float* Mean32 = (float*)alloc(2 * KN * 4);
    float* Sec32  = (float*)alloc(2 * KN * 4);

    // ---- small ----
    float* pm    = (float*)alloc(64 * NS * 4);
    float* ps    = (float*)alloc(64 * NS * 4);
    float* mxv   = (float*)alloc(NS * 4);
    float* invv  = (float*)alloc(NS * 4);
    float* cmean = (float*)alloc(1024 * 4);
    float* cinv  = (float*)alloc(1024 * 4);
    (void)ws_size; (void)in_sizes; (void)n_in; (void)out_size;

    // ================= pipeline =================
    packA_T<<<dim3(8, 8), 256, 0, stream>>>(f_w,   Wh[0], Wl[0], CH);
    packA_T<<<dim3(8, 8), 256, 0, stream>>>(g_w,   Wh[1], Wl[1], CH);
    packA_T<<<dim3(8, 8), 256, 0, stream>>>(h_w,   Wh[2], Wl[2], CH);
    packA_T<<<dim3(8, 8), 256, 0, stream>>>(out_w, Wh[3], Wl[3], CH);
    packB_k<false, true><<<dim3(16, 64, 2), 256, 0, stream>>>(content, Xc_hi, Xc_lo, nullptr, nullptr, NS, (long)KN, (long)KN);
    packB_k<false, true><<<dim3(16, 64, 2), 256, 0, stream>>>(style,   Xs_hi, Xs_lo, nullptr, nullptr, NS, (long)KN, (long)KN);
    content_stats<<<1024, 256, 0, stream>>>(content, cmean, cinv);

    // ---- merged conv3 (3-term): z = w*2 + b; w=0 (f,content)->Fqp hi, w=1 (g,style)
    //      ->Gkp hi, w=2 (h,style)->Hv32 fp32 ----
    {
        ZTab tb = {};
        const float* bs[3] = { f_b, g_b, h_b };
        for (int z = 0; z < 6; ++z) {
            const int w = z >> 1, b = z & 1;
            tb.aoff[z] = (long)(2 * w) * CHCH;
            tb.boff[z] = (w == 0 ? 0 : (long)(4 * KN)) + (long)b * KN;
            tb.mode[z] = (w < 2) ? 1 : 0;
            tb.np[z]   = 4;
            tb.ooff[z] = (w < 2) ? ((long)w * 2 * KN + (long)b * KN)   // u16 elems from Fqp_hi
                                 : ((long)4 * KN + (long)b * KN);      // fp32 elems from R5
            tb.bias[z] = bs[w];
        }
        gemm_split<4, false, false><<<dim3(32, 4, 6), 256, 0, stream>>>(
            Wh[0], Wh[0] + CHCH, Xc_hi, Xc_hi + 2 * KN, nullptr,
            (float*)R5, Fqp_hi, nullptr, nullptr, CH, NS, CH, tb);
    }

    // quantized-moments Hv packs (overwrites R2 phase-1; Xc/Xs dead)
    pack_hvT<<<dim3(64, 8, 2), 256, 0, stream>>>(Hv32, HvT_hi, Hv2T_hi, Hv2T_lo);

    for (int b = 0; b < 2; ++b) {
        const long bo = (long)b * KN;
        // QK^T (1-term): S^T[s][n] = sum_k Gk_hi[k][s] * Fq_hi[k][n]; fused col-stats
        ZTab tq = {};
        tq.np[0] = 2;
        gemm_split<2, false, true><<<dim3(32, 32, 1), 256, 0, stream>>>(
            Gkp_hi + bo, Gkp_hi, Fqp_hi + bo, nullptr, nullptr,
            S32, nullptr, pm, ps, NS, NS, CH, tq);
        colstats_comb64<<<16, 256, 0, stream>>>(pm, ps, mxv, invv);
        packB_k<true, false><<<dim3(16, 512, 1), 256, 0, stream>>>(
            S32, Pp + (size_t)b * NSNS, nullptr, mxv, invv, NS, 0, 0);
    }

    // ---- merged PV: z=0,1 -> Mean (A=HvT_hi, 1 term); z=2,3 -> Sec (A=Hv2T hi/lo, 2 terms) ----
    {
        ZTab tp = {};
        for (int z = 0; z < 4; ++z) {
            const int sec = (z >> 1), b = z & 1;
            tp.aoff[z] = (long)sec * 2 * KN + (long)b * KN;   // Ahi base R2; Alo base R2+2KN
            tp.boff[z] = (long)b * NSNS;
            tp.ooff[z] = (long)sec * 2 * KN + (long)b * KN;   // Mean32 / Sec32
            tp.np[z]   = sec ? 3 : 2;
        }
        gemm_split<3, false, false><<<dim3(32, 4, 4), 256, 0, stream>>>(
            R2, R2 + 2 * KN, Pp, nullptr, nullptr,
            Mean32, nullptr, nullptr, nullptr, CH, NS, NS, tp);
    }

    // O + fused pack (fp16 hi only)
    compute_O_pack<<<dim3(16, 64, 2), 256, 0, stream>>>(
        Mean32, Sec32, content, cmean, cinv, Op_hi);

    // ---- out conv (2-term: (Whi+Wlo)*O_hi): bias + residual(content) -> d_out ----
    {
        ZTab tf = {};
        for (int z = 0; z < 2; ++z) {
            tf.ooff[z] = (long)z * KN;
            tf.boff[z] = (long)z * KN;
            tf.np[z]   = 3;
            tf.bias[z] = out_b;
        }
        gemm_split<3, true, false><<<dim3(32, 4, 2), 256, 0, stream>>>(
            Wh[3], Wh[3] + CHCH, Op_hi, nullptr, content,
            out, nullptr, nullptr, nullptr, CH, NS, CH, tf);
    }
}

// Round 9
// 309.331 us; speedup vs baseline: 1.3476x; 1.3476x over previous
//
#include <hip/hip_runtime.h>
#include <math.h>

#define NS 4096
#define CH 512
#define EPSV 1e-5f

typedef __attribute__((ext_vector_type(8))) _Float16 f16x8;  // 8 x fp16 MFMA operand
typedef __attribute__((ext_vector_type(4))) float f32x4;     // MFMA accumulator
typedef unsigned short u16;

// ---------- fp16 helpers (RNE via cast) ----------
__device__ __forceinline__ u16 f2h(float x) {
    _Float16 h = (_Float16)x;
    return __builtin_bit_cast(unsigned short, h);
}
__device__ __forceinline__ float h2f(u16 b) {
    return (float)__builtin_bit_cast(_Float16, b);
}

// ---------- async global->LDS, 16B per lane ----------
__device__ __forceinline__ void gload16(const void* g, void* l) {
    __builtin_amdgcn_global_load_lds((const __attribute__((address_space(1))) unsigned*)g,
                                     (__attribute__((address_space(3))) unsigned*)l, 16, 0, 0);
}

// per-z dispatch table. np[z] = number of operand planes staged (prefix of
// [Ahi, Bhi, Alo, Blo]):
//   np=2 -> out = Ahi*Bhi                    (1 MFMA term)
//   np=3 -> out = (Ahi+Alo)*Bhi              (2 terms)
//   np=4 -> out = (Ahi+Alo)*Bhi + Ahi*Blo    (3 terms; ll ~2^-22 dropped)
// mode: 0 = fp32 out (+bias, +resid), 1 = packed fp16 HI-ONLY out [K/8][N][8].
struct ZTab {
    long aoff[6];
    long boff[6];
    long ooff[6];
    int  mode[6];
    int  np[6];
    const float* bias[6];
};

// =====================================================================================
// kloop<NPZ>: fully-unrolled compile-time staging + MFMA pipeline (the round-7 fast
// structure). 2-phase double-buffered; prefetch of tile t+1 issued before compute of t.
// =====================================================================================
template<int NPZ>
__device__ __forceinline__ void kloop(
    const u16* __restrict__ pAhi, const u16* __restrict__ pAlo,
    const u16* __restrict__ pBhi, const u16* __restrict__ pBlo,
    u16* smem, int smemStride,
    int Mw, int Nw, int K, int m0, int n0,
    int wid, int lane, int lk, int lm, int wm, int wn,
    f32x4 (&acc)[4][4])
{
    auto stage = [&](int buf, int ks) {
        const int kp0 = ks << 2;
        #pragma unroll
        for (int i = 0; i < 2 * NPZ; ++i) {
            const int q = i * 4 + wid;                 // wave-uniform
            const int b = q >> 3;                      // plane id (compile-time per i)
            const int p = (q & 7) >> 1;                // k-plane
            const int w = ((q & 1) << 6) + lane;       // width index 0..127
            const u16* src;
            if (b == 0)      src = pAhi + ((size_t)(kp0 + p) * Mw + m0 + w) * 8;
            else if (b == 1) src = pBhi + ((size_t)(kp0 + p) * Nw + n0 + w) * 8;
            else if (b == 2) src = pAlo + ((size_t)(kp0 + p) * Mw + m0 + w) * 8;
            else             src = pBlo + ((size_t)(kp0 + p) * Nw + n0 + w) * 8;
            gload16(src, &smem[(size_t)buf * smemStride + (size_t)(((b * 4 + p) * 128) + w) * 8]);
        }
    };

    const int nK = K >> 5;
    stage(0, 0);
    __syncthreads();                 // drains vmcnt(0): buf0 ready
    int cur = 0;
    for (int ks = 0; ks < nK; ++ks) {
        if (ks + 1 < nK) stage(cur ^ 1, ks + 1);   // prefetch next tile during MFMA
        const u16* sm = smem + (size_t)cur * smemStride;
        f16x8 ah[4], bh[4], al[4], bl[4];
        #pragma unroll
        for (int f = 0; f < 4; ++f) {
            ah[f] = *(const f16x8*)&sm[((0 * 4 + lk) * 128 + wm * 64 + f * 16 + lm) * 8];
            bh[f] = *(const f16x8*)&sm[((1 * 4 + lk) * 128 + wn * 64 + f * 16 + lm) * 8];
            if (NPZ >= 3)
                al[f] = *(const f16x8*)&sm[((2 * 4 + lk) * 128 + wm * 64 + f * 16 + lm) * 8];
            if (NPZ == 4)
                bl[f] = *(const f16x8*)&sm[((3 * 4 + lk) * 128 + wn * 64 + f * 16 + lm) * 8];
        }
        #pragma unroll
        for (int i = 0; i < 4; ++i)
            #pragma unroll
            for (int j = 0; j < 4; ++j) {
                acc[i][j] = __builtin_amdgcn_mfma_f32_16x16x32_f16(ah[i], bh[j], acc[i][j], 0, 0, 0);
                if (NPZ >= 3)
                    acc[i][j] = __builtin_amdgcn_mfma_f32_16x16x32_f16(al[i], bh[j], acc[i][j], 0, 0, 0);
                if (NPZ == 4)
                    acc[i][j] = __builtin_amdgcn_mfma_f32_16x16x32_f16(ah[i], bl[j], acc[i][j], 0, 0, 0);
            }
        __syncthreads();             // prefetched buffer complete, reads done
        cur ^= 1;
    }
}

// =====================================================================================
// Split-fp16 GEMM:  out[m][n] = sum_k A[k][m] * B[k][n]
// Packed operand layout: element (k, x) at ((k>>3)*W + x)*8 + (k&7)
// Tile 128x128, BK=32, 4 waves (2x2), per-wave 64x64 via 4x4 frags of 16x16x32.
// NP = max planes (LDS sizing); per-z plane count tab.np[z] selects a fully
// compile-time kloop instantiation via ONE block-uniform branch.
// COLST: epilogue emits per-column softmax partials (max, sum(exp)) per 64-row group.
// =====================================================================================
template<int NP, bool RESID, bool COLST>
__global__ __launch_bounds__(256, (NP == 2 ? 4 : (NP == 3 ? 3 : 2))) void gemm_split(
    const u16* __restrict__ Ahi, const u16* __restrict__ Alo,
    const u16* __restrict__ Bhi, const u16* __restrict__ Blo,
    const float* __restrict__ resid,
    float* __restrict__ outF, u16* __restrict__ outH,
    float* __restrict__ pmg, float* __restrict__ psg,
    int Mw, int Nw, int K, ZTab tab)
{
    __shared__ u16 smem[2][NP * 4 * 128 * 8];   // 2 x (NP*8KB) double buffer
    const int t = threadIdx.x;
    const int lane = t & 63;
    const int wid = t >> 6;
    const int wm = wid >> 1, wn = wid & 1;
    const int lk = lane >> 4, lm = lane & 15;
    const int m0 = blockIdx.y * 128, n0 = blockIdx.x * 128;
    const int z = blockIdx.z;
    const int npz = tab.np[z];
    const u16* pAhi = Ahi + tab.aoff[z];
    const u16* pAlo = Alo + tab.aoff[z];
    const u16* pBhi = Bhi + tab.boff[z];
    const u16* pBlo = (NP == 4) ? (Blo + tab.boff[z]) : nullptr;

    f32x4 acc[4][4] = {};
    const int smemStride = NP * 4 * 128 * 8;

    // ONE block-uniform branch into a fully compile-time pipeline.
    if constexpr (NP == 2) {
        kloop<2>(pAhi, pAlo, pBhi, pBlo, &smem[0][0], smemStride,
                 Mw, Nw, K, m0, n0, wid, lane, lk, lm, wm, wn, acc);
    } else if constexpr (NP == 3) {
        if (npz == 2)
            kloop<2>(pAhi, pAlo, pBhi, pBlo, &smem[0][0], smemStride,
                     Mw, Nw, K, m0, n0, wid, lane, lk, lm, wm, wn, acc);
        else
            kloop<3>(pAhi, pAlo, pBhi, pBlo, &smem[0][0], smemStride,
                     Mw, Nw, K, m0, n0, wid, lane, lk, lm, wm, wn, acc);
    } else {
        kloop<4>(pAhi, pAlo, pBhi, pBlo, &smem[0][0], smemStride,
                 Mw, Nw, K, m0, n0, wid, lane, lk, lm, wm, wn, acc);
    }

    // ---- epilogue: C/D layout col = lane&15, row = (lane>>4)*4 + reg ----
    const float* bp = tab.bias[z];
    if (tab.mode[z] == 0) {
        float* pout = outF + tab.ooff[z];
        #pragma unroll
        for (int i = 0; i < 4; ++i) {
            #pragma unroll
            for (int r = 0; r < 4; ++r) {
                const int m = m0 + wm * 64 + i * 16 + lk * 4 + r;
                const float bv = bp ? bp[m] : 0.f;
                const size_t ro = (size_t)m * Nw + n0 + wn * 64 + lm;
                #pragma unroll
                for (int j = 0; j < 4; ++j) {
                    float v = acc[i][j][r] + bv;
                    if (RESID) v += resid[tab.ooff[z] + ro + j * 16];
                    pout[ro + j * 16] = v;
                }
            }
        }
    } else {
        // packed fp16 hi-only out: element (k=m, x=n) -> ((m>>3)*Nw + n)*8 + (m&7)
        u16* ph = outH + tab.ooff[z];
        #pragma unroll
        for (int i = 0; i < 4; ++i) {
            float bv[4];
            #pragma unroll
            for (int r = 0; r < 4; ++r) {
                const int m = m0 + wm * 64 + i * 16 + lk * 4 + r;
                bv[r] = bp ? bp[m] : 0.f;
            }
            const long rg = (long)((m0 + wm * 64) >> 3) + i * 2 + (lk >> 1);
            const int sub = (lk & 1) * 4;
            #pragma unroll
            for (int j = 0; j < 4; ++j) {
                const int n = n0 + wn * 64 + j * 16 + lm;
                const long idx = (rg * Nw + n) * 8 + sub;
                u16 h[4];
                #pragma unroll
                for (int r = 0; r < 4; ++r)
                    h[r] = f2h(acc[i][j][r] + bv[r]);
                *(ushort4*)&ph[idx] = make_ushort4(h[0], h[1], h[2], h[3]);
            }
        }
    }
    if (COLST) {
        // per-column partial softmax stats over this wave-row's 64 s-rows.
        #pragma unroll
        for (int j = 0; j < 4; ++j) {
            float mx = -3.0e38f;
            #pragma unroll
            for (int i = 0; i < 4; ++i)
                #pragma unroll
                for (int r = 0; r < 4; ++r)
                    mx = fmaxf(mx, acc[i][j][r]);
            mx = fmaxf(mx, __shfl_xor(mx, 16));
            mx = fmaxf(mx, __shfl_xor(mx, 32));
            float sum = 0.f;
            #pragma unroll
            for (int i = 0; i < 4; ++i)
                #pragma unroll
                for (int r = 0; r < 4; ++r)
                    sum += __expf(acc[i][j][r] - mx);
            sum += __shfl_xor(sum, 16);
            sum += __shfl_xor(sum, 32);
            if (lk == 0) {
                const int n = n0 + wn * 64 + j * 16 + lm;
                const int grp = (m0 >> 6) + wm;          // 64 row-groups
                pmg[(size_t)grp * NS + n] = mx;
                psg[(size_t)grp * NS + n] = sum;
            }
        }
    }
}

// =====================================================================================
// packB: fp32 [K][N] (batched) -> fp16 hi(/lo) packed [K/8][N][8]. Optional fused exp.
// grid: (N/256, K/8, batches)
// =====================================================================================
template<bool EXPSC, bool WLO>
__global__ __launch_bounds__(256) void packB_k(const float* __restrict__ X,
    u16* __restrict__ Hi, u16* __restrict__ Lo,
    const float* __restrict__ mx, const float* __restrict__ inv,
    int Nw, long xB, long pB)
{
    const int n = blockIdx.x * 256 + threadIdx.x;
    const int p = blockIdx.y;
    const int z = blockIdx.z;
    const float* Xp = X + (size_t)z * xB + ((size_t)p * 8) * Nw + n;
    float em = 0.f, ei = 1.f;
    if (EXPSC) { em = mx[n]; ei = inv[n]; }
    u16 hi[8], lo[8];
    #pragma unroll
    for (int j = 0; j < 8; ++j) {
        float v = Xp[(size_t)j * Nw];
        if (EXPSC) v = __expf(v - em) * ei;
        u16 h = f2h(v);
        hi[j] = h;
        if (WLO) lo[j] = f2h(v - h2f(h));
    }
    const size_t o = (size_t)z * pB + ((size_t)p * Nw + n) * 8;
    *(uint4*)&Hi[o] = *(const uint4*)hi;
    if (WLO) *(uint4*)&Lo[o] = *(const uint4*)lo;
}

// =====================================================================================
// packA_T: weight W [M=512][K] fp32 -> transposed packed [K/8][512][8] hi/lo
// grid: (K/64, 512/64)
// =====================================================================================
__global__ __launch_bounds__(256) void packA_T(const float* __restrict__ W,
    u16* __restrict__ Hi, u16* __restrict__ Lo, int Kdim)
{
    __shared__ float tile[64][65];
    const int t = threadIdx.x;
    const int k0 = blockIdx.x * 64, m0 = blockIdx.y * 64;
    const int kk = t & 63, mb = t >> 6;
    #pragma unroll
    for (int it = 0; it < 16; ++it) {
        int mm = mb + it * 4;
        tile[mm][kk] = W[(size_t)(m0 + mm) * Kdim + k0 + kk];
    }
    __syncthreads();
    #pragma unroll
    for (int cc = 0; cc < 2; ++cc) {
        int c = t + cc * 256;
        int kp = c >> 6, m = c & 63;
        u16 hi[8], lo[8];
        #pragma unroll
        for (int j = 0; j < 8; ++j) {
            float v = tile[m][kp * 8 + j];
            u16 h = f2h(v);
            hi[j] = h;
            lo[j] = f2h(v - h2f(h));
        }
        size_t o = ((size_t)(k0 / 8 + kp) * CH + m0 + m) * 8;
        *(uint4*)&Hi[o] = *(const uint4*)hi;
        *(uint4*)&Lo[o] = *(const uint4*)lo;
    }
}

// =====================================================================================
// pack_hvT (quantized-moments form): Hv fp32 [C][N] ->
//   H1h = fp16(hv)                                  (Mean A-plane, 1 term)
//   H2h/H2l = hi/lo split of (fp16(hv))^2 (exact)   (Sec A-planes, 2 terms)
// Mean/Sec are EXACT moments of the quantized hv -> Var >= 0 structurally;
// dstd <= 2^-11 * RMS(hv) by Cauchy-Schwarz.
// grid: (N/64, C/64, 2=batch)
// =====================================================================================
__global__ __launch_bounds__(256) void pack_hvT(const float* __restrict__ Hv,
    u16* __restrict__ H1h, u16* __restrict__ H2h, u16* __restrict__ H2l)
{
    __shared__ float tile[64][65];
    const int t = threadIdx.x;
    const int s0 = blockIdx.x * 64, c0 = blockIdx.y * 64;
    const int z = blockIdx.z;
    const float* src = Hv + (size_t)z * CH * NS;
    const int ss = t & 63, cb = t >> 6;
    #pragma unroll
    for (int it = 0; it < 16; ++it) {
        int cc = cb + it * 4;
        tile[cc][ss] = src[(size_t)(c0 + cc) * NS + s0 + ss];
    }
    __syncthreads();
    const size_t zb = (size_t)z * NS * CH;
    #pragma unroll
    for (int cc2 = 0; cc2 < 2; ++cc2) {
        int c = t + cc2 * 256;
        int sp = c >> 6, cm = c & 63;
        u16 h1[8], h2[8], l2[8];
        #pragma unroll
        for (int j = 0; j < 8; ++j) {
            float v = tile[cm][sp * 8 + j];
            u16 a = f2h(v);
            h1[j] = a;
            float q = h2f(a);
            float q2 = q * q;              // <=22-bit mantissa: exact in fp32
            u16 b = f2h(q2);
            h2[j] = b;
            l2[j] = f2h(q2 - h2f(b));
        }
        size_t o = zb + ((size_t)(s0 / 8 + sp) * CH + c0 + cm) * 8;
        *(uint4*)&H1h[o] = *(const uint4*)h1;
        *(uint4*)&H2h[o] = *(const uint4*)h2;
        *(uint4*)&H2l[o] = *(const uint4*)l2;
    }
}

// =====================================================================================
// colstats_comb64: combine 64 row-group partials -> column max + 1/sum
// =====================================================================================
__global__ __launch_bounds__(256) void colstats_comb64(const float* __restrict__ pm,
    const float* __restrict__ ps, float* __restrict__ mx, float* __restrict__ inv)
{
    const int n = blockIdx.x * 256 + threadIdx.x;
    float m = -3.0e38f, s = 0.f;
    #pragma unroll 8
    for (int g = 0; g < 64; ++g) {
        float gm = pm[(size_t)g * NS + n], gs = ps[(size_t)g * NS + n];
        float nm = fmaxf(m, gm);
        s = s * __expf(m - nm) + gs * __expf(gm - nm);
        m = nm;
    }
    mx[n] = m;
    inv[n] = 1.f / s;
}

// ================= per-(b,c) content stats =================
__global__ __launch_bounds__(256) void content_stats(const float* __restrict__ content,
                                                     float* __restrict__ cmean,
                                                     float* __restrict__ cinv)
{
    const int bc = blockIdx.x;
    const float4* p = (const float4*)(content + (size_t)bc * NS);
    const int t = threadIdx.x;
    float s = 0.f, s2 = 0.f;
    #pragma unroll
    for (int j = 0; j < 4; ++j) {
        float4 v = p[t + j * 256];
        s  += (v.x + v.y) + (v.z + v.w);
        s2 += (v.x * v.x + v.y * v.y) + (v.z * v.z + v.w * v.w);
    }
    #pragma unroll
    for (int off = 32; off >= 1; off >>= 1) {
        s  += __shfl_xor(s, off);
        s2 += __shfl_xor(s2, off);
    }
    __shared__ float r1[4], r2[4];
    const int wid = t >> 6;
    if ((t & 63) == 0) { r1[wid] = s; r2[wid] = s2; }
    __syncthreads();
    if (t == 0) {
        s  = (r1[0] + r1[1]) + (r1[2] + r1[3]);
        s2 = (r2[0] + r2[1]) + (r2[2] + r2[3]);
        const float mean = s * (1.0f / 4096.f);
        const float var = (s2 - 4096.f * mean * mean) * (1.0f / 4095.f);
        cmean[bc] = mean;
        cinv[bc] = rsqrtf(fmaxf(var, 0.f) + EPSV);
    }
}

// =====================================================================================
// compute_O + fused O-pack (hi only): O = sqrt(max(Sec-Mean^2,0))*norm(content)+Mean,
// written packed fp16 [C/8][NS][8] per batch. grid: (NS/256, CH/8, 2)
// =====================================================================================
__global__ __launch_bounds__(256) void compute_O_pack(
    const float* __restrict__ Mean, const float* __restrict__ Sec,
    const float* __restrict__ content,
    const float* __restrict__ cmean, const float* __restrict__ cinv,
    u16* __restrict__ Oh)
{
    const int n  = blockIdx.x * 256 + threadIdx.x;
    const int cg = blockIdx.y;
    const int b  = blockIdx.z;
    const size_t KN = (size_t)CH * NS;
    u16 h[8];
    #pragma unroll
    for (int j = 0; j < 8; ++j) {
        const int c = cg * 8 + j;
        const size_t po = (size_t)b * KN + (size_t)c * NS + n;
        const float mn = Mean[po];
        const float sc = Sec[po];
        const float ct = content[po];
        const int bc = b * CH + c;
        const float o = sqrtf(fmaxf(sc - mn * mn, 0.f)) * ((ct - cmean[bc]) * cinv[bc]) + mn;
        h[j] = f2h(o);
    }
    const size_t off = (size_t)b * KN + ((size_t)cg * NS + n) * 8;
    *(uint4*)&Oh[off] = *(const uint4*)h;
}

// =====================================================================================
extern "C" void kernel_launch(void* const* d_in, const int* in_sizes, int n_in,
                              void* d_out, int out_size, void* d_ws, size_t ws_size,
                              hipStream_t stream)
{
    const float* content = (const float*)d_in[0];
    const float* style   = (const float*)d_in[1];
    const float* f_w   = (const float*)d_in[2];
    const float* f_b   = (const float*)d_in[3];
    const float* g_w   = (const float*)d_in[4];
    const float* g_b   = (const float*)d_in[5];
    const float* h_w   = (const float*)d_in[6];
    const float* h_b   = (const float*)d_in[7];
    const float* out_w = (const float*)d_in[8];
    const float* out_b = (const float*)d_in[9];
    float* out = (float*)d_out;

    char* ws = (char*)d_ws;
    size_t off = 0;
    auto alloc = [&](size_t bytes) -> void* {
        void* p = ws + off;
        off = (off + bytes + 255) & ~(size_t)255;
        return p;
    };

    const size_t KN   = (size_t)CH * NS;      // 2,097,152 elements (one batch plane)
    const size_t CHCH = (size_t)CH * CH;
    const long   NSNS = (long)NS * NS;

    // ---- weight packs: contiguous [Wh0 Wl0 Wh1 Wl1 Wh2 Wl2 Wh3 Wl3] ----
    u16 *Wh[4], *Wl[4];
    for (int w = 0; w < 4; ++w) { Wh[w] = (u16*)alloc(CHCH * 2); Wl[w] = (u16*)alloc(CHCH * 2); }

    // ---- R2: one 8*KN u16 region, two time-disjoint layouts:
    //   phase 1 (conv inputs):  [Xc_hi | Xc_lo | Xs_hi | Xs_lo]        (each 2KN)
    //   phase 2 (PV A-packs):   [HvT_hi | Hv2T_hi | Hv2T_lo]          (each 2KN)
    u16* R2 = (u16*)alloc(8 * KN * 2);
    u16* Xc_hi = R2;            u16* Xc_lo = R2 + 2 * KN;
    u16* Xs_hi = R2 + 4 * KN;   u16* Xs_lo = R2 + 6 * KN;
    u16* HvT_hi  = R2;                // Mean A-plane (1 term)
    u16* Hv2T_hi = R2 + 2 * KN;       // Sec A-hi
    u16* Hv2T_lo = R2 + 4 * KN;       // Sec A-lo

    // ---- R3: [Fqp_hi | Gkp_hi], each 2KN u16 (hi-only); Gkp reused as O pack ----
    u16* Fqp_hi = (u16*)alloc(2 * KN * 2);
    u16* Gkp_hi = (u16*)alloc(2 * KN * 2);
    u16* Op_hi  = Gkp_hi;

    // ---- R4: P packs (hi only), BOTH batches for merged PV ----
    u16* Pp = (u16*)alloc(2 * (size_t)NS * NS * 2);

    // ---- R5: fp32 union: Hv32 -> S32 (67.2 MB) ----
    char* R5 = (char*)alloc((size_t)NS * NS * 4);
    float* Hv32 = (float*)(R5 + 4 * KN * 4);   // conv z=4,5 output (dead after pack_hvT)
    float* S32  = (float*)R5;

    // ---- R6: Mean/Sec fp32, contiguous (Sec32 = Mean32 + 2KN floats) ----
    float* Mean32 = (float*)alloc(2 * KN * 4);
    float* Sec32  = (float*)alloc(2 * KN * 4);

    // ---- small ----
    float* pm    = (float*)alloc(64 * NS * 4);
    float* ps    = (float*)alloc(64 * NS * 4);
    float* mxv   = (float*)alloc(NS * 4);
    float* invv  = (float*)alloc(NS * 4);
    float* cmean = (float*)alloc(1024 * 4);
    float* cinv  = (float*)alloc(1024 * 4);
    (void)ws_size; (void)in_sizes; (void)n_in; (void)out_size;

    // ================= pipeline =================
    packA_T<<<dim3(8, 8), 256, 0, stream>>>(f_w,   Wh[0], Wl[0], CH);
    packA_T<<<dim3(8, 8), 256, 0, stream>>>(g_w,   Wh[1], Wl[1], CH);
    packA_T<<<dim3(8, 8), 256, 0, stream>>>(h_w,   Wh[2], Wl[2], CH);
    packA_T<<<dim3(8, 8), 256, 0, stream>>>(out_w, Wh[3], Wl[3], CH);
    packB_k<false, true><<<dim3(16, 64, 2), 256, 0, stream>>>(content, Xc_hi, Xc_lo, nullptr, nullptr, NS, (long)KN, (long)KN);
    packB_k<false, true><<<dim3(16, 64, 2), 256, 0, stream>>>(style,   Xs_hi, Xs_lo, nullptr, nullptr, NS, (long)KN, (long)KN);
    content_stats<<<1024, 256, 0, stream>>>(content, cmean, cinv);

    // ---- merged conv3 (3-term, np=4): z = w*2 + b; w=0 (f,content)->Fqp hi,
    //      w=1 (g,style)->Gkp hi, w=2 (h,style)->Hv32 fp32 ----
    {
        ZTab tb = {};
        const float* bs[3] = { f_b, g_b, h_b };
        for (int z = 0; z < 6; ++z) {
            const int w = z >> 1, b = z & 1;
            tb.aoff[z] = (long)(2 * w) * CHCH;
            tb.boff[z] = (w == 0 ? 0 : (long)(4 * KN)) + (long)b * KN;
            tb.mode[z] = (w < 2) ? 1 : 0;
            tb.np[z]   = 4;
            tb.ooff[z] = (w < 2) ? ((long)w * 2 * KN + (long)b * KN)   // u16 elems from Fqp_hi
                                 : ((long)4 * KN + (long)b * KN);      // fp32 elems from R5
            tb.bias[z] = bs[w];
        }
        gemm_split<4, false, false><<<dim3(32, 4, 6), 256, 0, stream>>>(
            Wh[0], Wh[0] + CHCH, Xc_hi, Xc_hi + 2 * KN, nullptr,
            (float*)R5, Fqp_hi, nullptr, nullptr, CH, NS, CH, tb);
    }

    // quantized-moments Hv packs (overwrites R2 phase-1; Xc/Xs dead)
    pack_hvT<<<dim3(64, 8, 2), 256, 0, stream>>>(Hv32, HvT_hi, Hv2T_hi, Hv2T_lo);

    for (int b = 0; b < 2; ++b) {
        const long bo = (long)b * KN;
        // QK^T (1-term, np=2): S^T[s][n] = sum_k Gk_hi[k][s] * Fq_hi[k][n]; fused col-stats
        ZTab tq = {};
        tq.np[0] = 2;
        gemm_split<2, false, true><<<dim3(32, 32, 1), 256, 0, stream>>>(
            Gkp_hi + bo, Gkp_hi, Fqp_hi + bo, nullptr, nullptr,
            S32, nullptr, pm, ps, NS, NS, CH, tq);
        colstats_comb64<<<16, 256, 0, stream>>>(pm, ps, mxv, invv);
        packB_k<true, false><<<dim3(16, 512, 1), 256, 0, stream>>>(
            S32, Pp + (size_t)b * NSNS, nullptr, mxv, invv, NS, 0, 0);
    }

    // ---- merged PV: z=0,1 -> Mean (A=HvT_hi, np=2); z=2,3 -> Sec (A=Hv2T hi/lo, np=3) ----
    {
        ZTab tp = {};
        for (int z = 0; z < 4; ++z) {
            const int sec = (z >> 1), b = z & 1;
            tp.aoff[z] = (long)sec * 2 * KN + (long)b * KN;   // Ahi base R2; Alo base R2+2KN
            tp.boff[z] = (long)b * NSNS;
            tp.ooff[z] = (long)sec * 2 * KN + (long)b * KN;   // Mean32 / Sec32
            tp.np[z]   = sec ? 3 : 2;
        }
        gemm_split<3, false, false><<<dim3(32, 4, 4), 256, 0, stream>>>(
            R2, R2 + 2 * KN, Pp, nullptr, nullptr,
            Mean32, nullptr, nullptr, nullptr, CH, NS, NS, tp);
    }

    // O + fused pack (fp16 hi only)
    compute_O_pack<<<dim3(16, 64, 2), 256, 0, stream>>>(
        Mean32, Sec32, content, cmean, cinv, Op_hi);

    // ---- out conv (2-term, np=3: (Whi+Wlo)*O_hi): bias + residual(content) -> d_out ----
    {
        ZTab tf = {};
        for (int z = 0; z < 2; ++z) {
            tf.ooff[z] = (long)z * KN;
            tf.boff[z] = (long)z * KN;
            tf.np[z]   = 3;
            tf.bias[z] = out_b;
        }
        gemm_split<3, true, false><<<dim3(32, 4, 2), 256, 0, stream>>>(
            Wh[3], Wh[3] + CHCH, Op_hi, nullptr, content,
            out, nullptr, nullptr, nullptr, CH, NS, CH, tf);
    }
}

// Round 10
// 262.721 us; speedup vs baseline: 1.5867x; 1.1774x over previous
//
#include <hip/hip_runtime.h>
#include <math.h>

#define NS 4096
#define CH 512
#define EPSV 1e-5f

typedef __attribute__((ext_vector_type(8))) _Float16 f16x8;  // 8 x fp16 MFMA operand
typedef __attribute__((ext_vector_type(4))) float f32x4;     // MFMA accumulator
typedef unsigned short u16;

// ---------- fp16 helpers (RNE via cast) ----------
__device__ __forceinline__ u16 f2h(float x) {
    _Float16 h = (_Float16)x;
    return __builtin_bit_cast(unsigned short, h);
}
__device__ __forceinline__ float h2f(u16 b) {
    return (float)__builtin_bit_cast(_Float16, b);
}

// ---------- async global->LDS, 16B per lane ----------
__device__ __forceinline__ void gload16(const void* g, void* l) {
    __builtin_amdgcn_global_load_lds((const __attribute__((address_space(1))) unsigned*)g,
                                     (__attribute__((address_space(3))) unsigned*)l, 16, 0, 0);
}

// per-z dispatch table. np[z] = number of operand planes staged (prefix of
// [Ahi, Bhi, Alo, Blo]):
//   np=2 -> out = Ahi*Bhi                    (1 MFMA term)
//   np=3 -> out = (Ahi+Alo)*Bhi              (2 terms)
//   np=4 -> out = (Ahi+Alo)*Bhi + Ahi*Blo    (3 terms)
// mode: 0 = fp32 out (+bias, +resid), 1 = packed fp16 HI-ONLY out [K/8][N][8].
// COLST kernels ignore mode: they store fp16(acc - groupmax) packed + stats.
struct ZTab {
    long aoff[6];
    long boff[6];
    long ooff[6];
    int  mode[6];
    int  np[6];
    const float* bias[6];
};

// =====================================================================================
// kloop<NPZ>: fully-unrolled compile-time staging + MFMA pipeline.
// 2-phase double-buffered; prefetch of tile t+1 issued before compute of t.
// =====================================================================================
template<int NPZ>
__device__ __forceinline__ void kloop(
    const u16* __restrict__ pAhi, const u16* __restrict__ pAlo,
    const u16* __restrict__ pBhi, const u16* __restrict__ pBlo,
    u16* smem, int smemStride,
    int Mw, int Nw, int K, int m0, int n0,
    int wid, int lane, int lk, int lm, int wm, int wn,
    f32x4 (&acc)[4][4])
{
    auto stage = [&](int buf, int ks) {
        const int kp0 = ks << 2;
        #pragma unroll
        for (int i = 0; i < 2 * NPZ; ++i) {
            const int q = i * 4 + wid;                 // wave-uniform
            const int b = q >> 3;                      // plane id (compile-time per i)
            const int p = (q & 7) >> 1;                // k-plane
            const int w = ((q & 1) << 6) + lane;       // width index 0..127
            const u16* src;
            if (b == 0)      src = pAhi + ((size_t)(kp0 + p) * Mw + m0 + w) * 8;
            else if (b == 1) src = pBhi + ((size_t)(kp0 + p) * Nw + n0 + w) * 8;
            else if (b == 2) src = pAlo + ((size_t)(kp0 + p) * Mw + m0 + w) * 8;
            else             src = pBlo + ((size_t)(kp0 + p) * Nw + n0 + w) * 8;
            gload16(src, &smem[(size_t)buf * smemStride + (size_t)(((b * 4 + p) * 128) + w) * 8]);
        }
    };

    const int nK = K >> 5;
    stage(0, 0);
    __syncthreads();                 // drains vmcnt(0): buf0 ready
    int cur = 0;
    for (int ks = 0; ks < nK; ++ks) {
        if (ks + 1 < nK) stage(cur ^ 1, ks + 1);   // prefetch next tile during MFMA
        const u16* sm = smem + (size_t)cur * smemStride;
        f16x8 ah[4], bh[4], al[4], bl[4];
        #pragma unroll
        for (int f = 0; f < 4; ++f) {
            ah[f] = *(const f16x8*)&sm[((0 * 4 + lk) * 128 + wm * 64 + f * 16 + lm) * 8];
            bh[f] = *(const f16x8*)&sm[((1 * 4 + lk) * 128 + wn * 64 + f * 16 + lm) * 8];
            if (NPZ >= 3)
                al[f] = *(const f16x8*)&sm[((2 * 4 + lk) * 128 + wm * 64 + f * 16 + lm) * 8];
            if (NPZ == 4)
                bl[f] = *(const f16x8*)&sm[((3 * 4 + lk) * 128 + wn * 64 + f * 16 + lm) * 8];
        }
        #pragma unroll
        for (int i = 0; i < 4; ++i)
            #pragma unroll
            for (int j = 0; j < 4; ++j) {
                acc[i][j] = __builtin_amdgcn_mfma_f32_16x16x32_f16(ah[i], bh[j], acc[i][j], 0, 0, 0);
                if (NPZ >= 3)
                    acc[i][j] = __builtin_amdgcn_mfma_f32_16x16x32_f16(al[i], bh[j], acc[i][j], 0, 0, 0);
                if (NPZ == 4)
                    acc[i][j] = __builtin_amdgcn_mfma_f32_16x16x32_f16(ah[i], bl[j], acc[i][j], 0, 0, 0);
            }
        __syncthreads();             // prefetched buffer complete, reads done
        cur ^= 1;
    }
}

// =====================================================================================
// Split-fp16 GEMM:  out[m][n] = sum_k A[k][m] * B[k][n]
// Packed operand layout: element (k, x) at ((k>>3)*W + x)*8 + (k&7)
// Tile 128x128, BK=32, 4 waves (2x2), per-wave 64x64 via 4x4 frags of 16x16x32.
// COLST (QK): per-column softmax partials (max, sum(exp)) over each 64-row group
// (z-batch offset applied), then stores fp16(acc - groupmax) in packed layout.
// =====================================================================================
template<int NP, bool RESID, bool COLST>
__global__ __launch_bounds__(256, (NP == 2 ? 4 : (NP == 3 ? 3 : 2))) void gemm_split(
    const u16* __restrict__ Ahi, const u16* __restrict__ Alo,
    const u16* __restrict__ Bhi, const u16* __restrict__ Blo,
    const float* __restrict__ resid,
    float* __restrict__ outF, u16* __restrict__ outH,
    float* __restrict__ pmg, float* __restrict__ psg,
    int Mw, int Nw, int K, ZTab tab)
{
    __shared__ u16 smem[2][NP * 4 * 128 * 8];   // 2 x (NP*8KB) double buffer
    const int t = threadIdx.x;
    const int lane = t & 63;
    const int wid = t >> 6;
    const int wm = wid >> 1, wn = wid & 1;
    const int lk = lane >> 4, lm = lane & 15;
    const int m0 = blockIdx.y * 128, n0 = blockIdx.x * 128;
    const int z = blockIdx.z;
    const int npz = tab.np[z];
    const u16* pAhi = Ahi + tab.aoff[z];
    const u16* pAlo = Alo + tab.aoff[z];
    const u16* pBhi = Bhi + tab.boff[z];
    const u16* pBlo = (NP == 4) ? (Blo + tab.boff[z]) : nullptr;

    f32x4 acc[4][4] = {};
    const int smemStride = NP * 4 * 128 * 8;

    if constexpr (NP == 2) {
        kloop<2>(pAhi, pAlo, pBhi, pBlo, &smem[0][0], smemStride,
                 Mw, Nw, K, m0, n0, wid, lane, lk, lm, wm, wn, acc);
    } else if constexpr (NP == 3) {
        if (npz == 2)
            kloop<2>(pAhi, pAlo, pBhi, pBlo, &smem[0][0], smemStride,
                     Mw, Nw, K, m0, n0, wid, lane, lk, lm, wm, wn, acc);
        else
            kloop<3>(pAhi, pAlo, pBhi, pBlo, &smem[0][0], smemStride,
                     Mw, Nw, K, m0, n0, wid, lane, lk, lm, wm, wn, acc);
    } else {
        kloop<4>(pAhi, pAlo, pBhi, pBlo, &smem[0][0], smemStride,
                 Mw, Nw, K, m0, n0, wid, lane, lk, lm, wm, wn, acc);
    }

    // ---- epilogue: C/D layout col = lane&15, row = (lane>>4)*4 + reg ----
    const float* bp = tab.bias[z];
    if (COLST) {
        // 1) per-column stats over this wave-row's 64 s-rows (before store).
        float mxj[4];
        #pragma unroll
        for (int j = 0; j < 4; ++j) {
            float mx = -3.0e38f;
            #pragma unroll
            for (int i = 0; i < 4; ++i)
                #pragma unroll
                for (int r = 0; r < 4; ++r)
                    mx = fmaxf(mx, acc[i][j][r]);
            mx = fmaxf(mx, __shfl_xor(mx, 16));
            mx = fmaxf(mx, __shfl_xor(mx, 32));
            mxj[j] = mx;
            float sum = 0.f;
            #pragma unroll
            for (int i = 0; i < 4; ++i)
                #pragma unroll
                for (int r = 0; r < 4; ++r)
                    sum += __expf(acc[i][j][r] - mx);
            sum += __shfl_xor(sum, 16);
            sum += __shfl_xor(sum, 32);
            if (lk == 0) {
                const int n = n0 + wn * 64 + j * 16 + lm;
                const int grp = (m0 >> 6) + wm;          // 64 row-groups per batch
                pmg[((size_t)z * 64 + grp) * NS + n] = mx;
                psg[((size_t)z * 64 + grp) * NS + n] = sum;
            }
        }
        // 2) shifted fp16 store, packed layout (k=m): ((m>>3)*Nw + n)*8 + (m&7)
        u16* ph = outH + tab.ooff[z];
        #pragma unroll
        for (int i = 0; i < 4; ++i) {
            const long rg = (long)((m0 + wm * 64) >> 3) + i * 2 + (lk >> 1);
            const int sub = (lk & 1) * 4;
            #pragma unroll
            for (int j = 0; j < 4; ++j) {
                const int n = n0 + wn * 64 + j * 16 + lm;
                const long idx = (rg * Nw + n) * 8 + sub;
                u16 h[4];
                #pragma unroll
                for (int r = 0; r < 4; ++r)
                    h[r] = f2h(acc[i][j][r] - mxj[j]);
                *(ushort4*)&ph[idx] = make_ushort4(h[0], h[1], h[2], h[3]);
            }
        }
    } else if (tab.mode[z] == 0) {
        float* pout = outF + tab.ooff[z];
        #pragma unroll
        for (int i = 0; i < 4; ++i) {
            #pragma unroll
            for (int r = 0; r < 4; ++r) {
                const int m = m0 + wm * 64 + i * 16 + lk * 4 + r;
                const float bv = bp ? bp[m] : 0.f;
                const size_t ro = (size_t)m * Nw + n0 + wn * 64 + lm;
                #pragma unroll
                for (int j = 0; j < 4; ++j) {
                    float v = acc[i][j][r] + bv;
                    if (RESID) v += resid[tab.ooff[z] + ro + j * 16];
                    pout[ro + j * 16] = v;
                }
            }
        }
    } else {
        // packed fp16 hi-only out: element (k=m, x=n) -> ((m>>3)*Nw + n)*8 + (m&7)
        u16* ph = outH + tab.ooff[z];
        #pragma unroll
        for (int i = 0; i < 4; ++i) {
            float bv[4];
            #pragma unroll
            for (int r = 0; r < 4; ++r) {
                const int m = m0 + wm * 64 + i * 16 + lk * 4 + r;
                bv[r] = bp ? bp[m] : 0.f;
            }
            const long rg = (long)((m0 + wm * 64) >> 3) + i * 2 + (lk >> 1);
            const int sub = (lk & 1) * 4;
            #pragma unroll
            for (int j = 0; j < 4; ++j) {
                const int n = n0 + wn * 64 + j * 16 + lm;
                const long idx = (rg * Nw + n) * 8 + sub;
                u16 h[4];
                #pragma unroll
                for (int r = 0; r < 4; ++r)
                    h[r] = f2h(acc[i][j][r] + bv[r]);
                *(ushort4*)&ph[idx] = make_ushort4(h[0], h[1], h[2], h[3]);
            }
        }
    }
}

// =====================================================================================
// packB: fp32 [K][N] (batched) -> fp16 hi packed [K/8][N][8] (hi-only for conv inputs).
// grid: (N/256, K/8, batches)
// =====================================================================================
__global__ __launch_bounds__(256) void packB_k(const float* __restrict__ X,
    u16* __restrict__ Hi, int Nw, long xB, long pB)
{
    const int n = blockIdx.x * 256 + threadIdx.x;
    const int p = blockIdx.y;
    const int z = blockIdx.z;
    const float* Xp = X + (size_t)z * xB + ((size_t)p * 8) * Nw + n;
    u16 hi[8];
    #pragma unroll
    for (int j = 0; j < 8; ++j)
        hi[j] = f2h(Xp[(size_t)j * Nw]);
    const size_t o = (size_t)z * pB + ((size_t)p * Nw + n) * 8;
    *(uint4*)&Hi[o] = *(const uint4*)hi;
}

// =====================================================================================
// pack_P: packed fp16 S16 (group-max-shifted) -> packed fp16 P = exp(s+gm-gmax)*inv
// grid: (NS/256, NS/8, 2=batch). Same packed layout in and out.
// =====================================================================================
__global__ __launch_bounds__(256) void pack_P(const u16* __restrict__ S16,
    const float* __restrict__ pm, const float* __restrict__ mxv,
    const float* __restrict__ invv, u16* __restrict__ Pp)
{
    const int n = blockIdx.x * 256 + threadIdx.x;
    const int rg = blockIdx.y;                 // s>>3
    const int z = blockIdx.z;
    const long NSNS = (long)NS * NS;
    const int g = rg >> 3;                     // s>>6
    const float shift = pm[((size_t)z * 64 + g) * NS + n] - mxv[(size_t)z * NS + n];
    const float inv = invv[(size_t)z * NS + n];
    const size_t idx = (size_t)z * NSNS + ((size_t)rg * NS + n) * 8;
    uint4 sv = *(const uint4*)&S16[idx];
    const u16* s = (const u16*)&sv;
    u16 p[8];
    #pragma unroll
    for (int j = 0; j < 8; ++j)
        p[j] = f2h(__expf(h2f(s[j]) + shift) * inv);
    *(uint4*)&Pp[idx] = *(const uint4*)p;
}

// =====================================================================================
// packA_T: weight W [M=512][K] fp32 -> transposed packed [K/8][512][8] hi/lo
// grid: (K/64, 512/64)
// =====================================================================================
__global__ __launch_bounds__(256) void packA_T(const float* __restrict__ W,
    u16* __restrict__ Hi, u16* __restrict__ Lo, int Kdim)
{
    __shared__ float tile[64][65];
    const int t = threadIdx.x;
    const int k0 = blockIdx.x * 64, m0 = blockIdx.y * 64;
    const int kk = t & 63, mb = t >> 6;
    #pragma unroll
    for (int it = 0; it < 16; ++it) {
        int mm = mb + it * 4;
        tile[mm][kk] = W[(size_t)(m0 + mm) * Kdim + k0 + kk];
    }
    __syncthreads();
    #pragma unroll
    for (int cc = 0; cc < 2; ++cc) {
        int c = t + cc * 256;
        int kp = c >> 6, m = c & 63;
        u16 hi[8], lo[8];
        #pragma unroll
        for (int j = 0; j < 8; ++j) {
            float v = tile[m][kp * 8 + j];
            u16 h = f2h(v);
            hi[j] = h;
            lo[j] = f2h(v - h2f(h));
        }
        size_t o = ((size_t)(k0 / 8 + kp) * CH + m0 + m) * 8;
        *(uint4*)&Hi[o] = *(const uint4*)hi;
        *(uint4*)&Lo[o] = *(const uint4*)lo;
    }
}

// =====================================================================================
// pack_hvT (quantized-moments form): Hv fp32 [C][N] ->
//   H1h = fp16(hv)                                  (Mean A-plane, 1 term)
//   H2h/H2l = hi/lo split of (fp16(hv))^2 (exact)   (Sec A-planes, 2 terms)
// grid: (N/64, C/64, 2=batch)
// =====================================================================================
__global__ __launch_bounds__(256) void pack_hvT(const float* __restrict__ Hv,
    u16* __restrict__ H1h, u16* __restrict__ H2h, u16* __restrict__ H2l)
{
    __shared__ float tile[64][65];
    const int t = threadIdx.x;
    const int s0 = blockIdx.x * 64, c0 = blockIdx.y * 64;
    const int z = blockIdx.z;
    const float* src = Hv + (size_t)z * CH * NS;
    const int ss = t & 63, cb = t >> 6;
    #pragma unroll
    for (int it = 0; it < 16; ++it) {
        int cc = cb + it * 4;
        tile[cc][ss] = src[(size_t)(c0 + cc) * NS + s0 + ss];
    }
    __syncthreads();
    const size_t zb = (size_t)z * NS * CH;
    #pragma unroll
    for (int cc2 = 0; cc2 < 2; ++cc2) {
        int c = t + cc2 * 256;
        int sp = c >> 6, cm = c & 63;
        u16 h1[8], h2[8], l2[8];
        #pragma unroll
        for (int j = 0; j < 8; ++j) {
            float v = tile[cm][sp * 8 + j];
            u16 a = f2h(v);
            h1[j] = a;
            float q = h2f(a);
            float q2 = q * q;              // <=22-bit mantissa: exact in fp32
            u16 b = f2h(q2);
            h2[j] = b;
            l2[j] = f2h(q2 - h2f(b));
        }
        size_t o = zb + ((size_t)(s0 / 8 + sp) * CH + c0 + cm) * 8;
        *(uint4*)&H1h[o] = *(const uint4*)h1;
        *(uint4*)&H2h[o] = *(const uint4*)h2;
        *(uint4*)&H2l[o] = *(const uint4*)l2;
    }
}

// =====================================================================================
// colstats_comb64: combine 64 row-group partials -> column max + 1/sum. grid (16, 2)
// =====================================================================================
__global__ __launch_bounds__(256) void colstats_comb64(const float* __restrict__ pm,
    const float* __restrict__ ps, float* __restrict__ mx, float* __restrict__ inv)
{
    const int n = blockIdx.x * 256 + threadIdx.x;
    const int z = blockIdx.y;
    float m = -3.0e38f, s = 0.f;
    #pragma unroll 8
    for (int g = 0; g < 64; ++g) {
        float gm = pm[((size_t)z * 64 + g) * NS + n], gs = ps[((size_t)z * 64 + g) * NS + n];
        float nm = fmaxf(m, gm);
        s = s * __expf(m - nm) + gs * __expf(gm - nm);
        m = nm;
    }
    mx[(size_t)z * NS + n] = m;
    inv[(size_t)z * NS + n] = 1.f / s;
}

// ================= per-(b,c) content stats =================
__global__ __launch_bounds__(256) void content_stats(const float* __restrict__ content,
                                                     float* __restrict__ cmean,
                                                     float* __restrict__ cinv)
{
    const int bc = blockIdx.x;
    const float4* p = (const float4*)(content + (size_t)bc * NS);
    const int t = threadIdx.x;
    float s = 0.f, s2 = 0.f;
    #pragma unroll
    for (int j = 0; j < 4; ++j) {
        float4 v = p[t + j * 256];
        s  += (v.x + v.y) + (v.z + v.w);
        s2 += (v.x * v.x + v.y * v.y) + (v.z * v.z + v.w * v.w);
    }
    #pragma unroll
    for (int off = 32; off >= 1; off >>= 1) {
        s  += __shfl_xor(s, off);
        s2 += __shfl_xor(s2, off);
    }
    __shared__ float r1[4], r2[4];
    const int wid = t >> 6;
    if ((t & 63) == 0) { r1[wid] = s; r2[wid] = s2; }
    __syncthreads();
    if (t == 0) {
        s  = (r1[0] + r1[1]) + (r1[2] + r1[3]);
        s2 = (r2[0] + r2[1]) + (r2[2] + r2[3]);
        const float mean = s * (1.0f / 4096.f);
        const float var = (s2 - 4096.f * mean * mean) * (1.0f / 4095.f);
        cmean[bc] = mean;
        cinv[bc] = rsqrtf(fmaxf(var, 0.f) + EPSV);
    }
}

// =====================================================================================
// compute_O + fused O-pack (hi only): O = sqrt(max(Sec-Mean^2,0))*norm(content)+Mean,
// written packed fp16 [C/8][NS][8] per batch. grid: (NS/256, CH/8, 2)
// =====================================================================================
__global__ __launch_bounds__(256) void compute_O_pack(
    const float* __restrict__ Mean, const float* __restrict__ Sec,
    const float* __restrict__ content,
    const float* __restrict__ cmean, const float* __restrict__ cinv,
    u16* __restrict__ Oh)
{
    const int n  = blockIdx.x * 256 + threadIdx.x;
    const int cg = blockIdx.y;
    const int b  = blockIdx.z;
    const size_t KN = (size_t)CH * NS;
    u16 h[8];
    #pragma unroll
    for (int j = 0; j < 8; ++j) {
        const int c = cg * 8 + j;
        const size_t po = (size_t)b * KN + (size_t)c * NS + n;
        const float mn = Mean[po];
        const float sc = Sec[po];
        const float ct = content[po];
        const int bc = b * CH + c;
        const float o = sqrtf(fmaxf(sc - mn * mn, 0.f)) * ((ct - cmean[bc]) * cinv[bc]) + mn;
        h[j] = f2h(o);
    }
    const size_t off = (size_t)b * KN + ((size_t)cg * NS + n) * 8;
    *(uint4*)&Oh[off] = *(const uint4*)h;
}

// =====================================================================================
extern "C" void kernel_launch(void* const* d_in, const int* in_sizes, int n_in,
                              void* d_out, int out_size, void* d_ws, size_t ws_size,
                              hipStream_t stream)
{
    const float* content = (const float*)d_in[0];
    const float* style   = (const float*)d_in[1];
    const float* f_w   = (const float*)d_in[2];
    const float* f_b   = (const float*)d_in[3];
    const float* g_w   = (const float*)d_in[4];
    const float* g_b   = (const float*)d_in[5];
    const float* h_w   = (const float*)d_in[6];
    const float* h_b   = (const float*)d_in[7];
    const float* out_w = (const float*)d_in[8];
    const float* out_b = (const float*)d_in[9];
    float* out = (float*)d_out;

    char* ws = (char*)d_ws;
    size_t off = 0;
    auto alloc = [&](size_t bytes) -> void* {
        void* p = ws + off;
        off = (off + bytes + 255) & ~(size_t)255;
        return p;
    };

    const size_t KN   = (size_t)CH * NS;      // 2,097,152 elements (one batch plane)
    const size_t CHCH = (size_t)CH * CH;
    const long   NSNS = (long)NS * NS;

    // ---- weight packs: contiguous [Wh0 Wl0 Wh1 Wl1 Wh2 Wl2 Wh3 Wl3] ----
    u16 *Wh[4], *Wl[4];
    for (int w = 0; w < 4; ++w) { Wh[w] = (u16*)alloc(CHCH * 2); Wl[w] = (u16*)alloc(CHCH * 2); }

    // ---- R2: one 8*KN u16 region, two time-disjoint layouts:
    //   phase 1 (conv inputs, hi-only):  [Xc_hi | Xs_hi]                (each 2KN)
    //   phase 2 (PV A-packs):            [HvT_hi | Hv2T_hi | Hv2T_lo]  (each 2KN)
    u16* R2 = (u16*)alloc(8 * KN * 2);
    u16* Xc_hi = R2;
    u16* Xs_hi = R2 + 2 * KN;
    u16* HvT_hi  = R2;                // Mean A-plane (1 term)
    u16* Hv2T_hi = R2 + 2 * KN;       // Sec A-hi
    u16* Hv2T_lo = R2 + 4 * KN;       // Sec A-lo

    // ---- R3: [Fqp_hi | Gkp_hi], each 2KN u16; Gkp reused as O pack ----
    u16* Fqp_hi = (u16*)alloc(2 * KN * 2);
    u16* Gkp_hi = (u16*)alloc(2 * KN * 2);
    u16* Op_hi  = Gkp_hi;

    // ---- R4: P packs (hi only), BOTH batches for merged PV ----
    u16* Pp = (u16*)alloc(2 * (size_t)NS * NS * 2);

    // ---- R5: union: Hv32 fp32 (during convs) -> S16 both batches (67 MB) ----
    char* R5 = (char*)alloc(2 * (size_t)NS * NS * 2);
    float* Hv32 = (float*)(R5 + 4 * KN * 4);   // conv z=4,5 output (dead after pack_hvT)
    u16*   S16  = (u16*)R5;                    // QK output, group-max-shifted fp16

    // ---- R6: Mean/Sec fp32, contiguous (Sec32 = Mean32 + 2KN floats) ----
    float* Mean32 = (float*)alloc(2 * KN * 4);
    float* Sec32  = (float*)alloc(2 * KN * 4);

    // ---- small ----
    float* pm    = (float*)alloc(2 * 64 * NS * 4);
    float* ps    = (float*)alloc(2 * 64 * NS * 4);
    float* mxv   = (float*)alloc(2 * NS * 4);
    float* invv  = (float*)alloc(2 * NS * 4);
    float* cmean = (float*)alloc(1024 * 4);
    float* cinv  = (float*)alloc(1024 * 4);
    (void)ws_size; (void)in_sizes; (void)n_in; (void)out_size;

    // ================= pipeline =================
    packA_T<<<dim3(8, 8), 256, 0, stream>>>(f_w,   Wh[0], Wl[0], CH);
    packA_T<<<dim3(8, 8), 256, 0, stream>>>(g_w,   Wh[1], Wl[1], CH);
    packA_T<<<dim3(8, 8), 256, 0, stream>>>(h_w,   Wh[2], Wl[2], CH);
    packA_T<<<dim3(8, 8), 256, 0, stream>>>(out_w, Wh[3], Wl[3], CH);
    packB_k<<<dim3(16, 64, 2), 256, 0, stream>>>(content, Xc_hi, NS, (long)KN, (long)KN);
    packB_k<<<dim3(16, 64, 2), 256, 0, stream>>>(style,   Xs_hi, NS, (long)KN, (long)KN);
    content_stats<<<1024, 256, 0, stream>>>(content, cmean, cinv);

    // ---- merged conv3 (2-term, np=3: (Whi+Wlo)*Xhi): z = w*2 + b;
    //      w=0 (f,content)->Fqp hi, w=1 (g,style)->Gkp hi, w=2 (h,style)->Hv32 fp32 ----
    {
        ZTab tb = {};
        const float* bs[3] = { f_b, g_b, h_b };
        for (int z = 0; z < 6; ++z) {
            const int w = z >> 1, b = z & 1;
            tb.aoff[z] = (long)(2 * w) * CHCH;
            tb.boff[z] = (w == 0 ? 0 : (long)(2 * KN)) + (long)b * KN;
            tb.mode[z] = (w < 2) ? 1 : 0;
            tb.np[z]   = 3;
            tb.ooff[z] = (w < 2) ? ((long)w * 2 * KN + (long)b * KN)   // u16 elems from Fqp_hi
                                 : ((long)4 * KN + (long)b * KN);      // fp32 elems from R5
            tb.bias[z] = bs[w];
        }
        gemm_split<3, false, false><<<dim3(32, 4, 6), 256, 0, stream>>>(
            Wh[0], Wh[0] + CHCH, Xc_hi, nullptr, nullptr,
            (float*)R5, Fqp_hi, nullptr, nullptr, CH, NS, CH, tb);
    }

    // quantized-moments Hv packs (overwrites R2 phase-1; Xc/Xs dead)
    pack_hvT<<<dim3(64, 8, 2), 256, 0, stream>>>(Hv32, HvT_hi, Hv2T_hi, Hv2T_lo);

    // ---- merged QK (1-term, np=2, z=2 batches): S16 = fp16(S - groupmax), packed;
    //      fused per-group col-stats ----
    {
        ZTab tq = {};
        for (int z = 0; z < 2; ++z) {
            tq.aoff[z] = (long)z * KN;     // Gk batch
            tq.boff[z] = (long)z * KN;     // Fq batch
            tq.ooff[z] = (long)z * NSNS;   // S16 batch (u16 elems)
            tq.np[z]   = 2;
        }
        gemm_split<2, false, true><<<dim3(32, 32, 2), 256, 0, stream>>>(
            Gkp_hi, nullptr, Fqp_hi, nullptr, nullptr,
            nullptr, S16, pm, ps, NS, NS, CH, tq);
    }
    colstats_comb64<<<dim3(16, 2), 256, 0, stream>>>(pm, ps, mxv, invv);
    pack_P<<<dim3(16, 512, 2), 256, 0, stream>>>(S16, pm, mxv, invv, Pp);

    // ---- merged PV: z=0,1 -> Mean (A=HvT_hi, np=2); z=2,3 -> Sec (A=Hv2T hi/lo, np=3) ----
    {
        ZTab tp = {};
        for (int z = 0; z < 4; ++z) {
            const int sec = (z >> 1), b = z & 1;
            tp.aoff[z] = (long)sec * 2 * KN + (long)b * KN;   // Ahi base R2; Alo base R2+2KN
            tp.boff[z] = (long)b * NSNS;
            tp.ooff[z] = (long)sec * 2 * KN + (long)b * KN;   // Mean32 / Sec32
            tp.np[z]   = sec ? 3 : 2;
        }
        gemm_split<3, false, false><<<dim3(32, 4, 4), 256, 0, stream>>>(
            R2, R2 + 2 * KN, Pp, nullptr, nullptr,
            Mean32, nullptr, nullptr, nullptr, CH, NS, NS, tp);
    }

    // O + fused pack (fp16 hi only)
    compute_O_pack<<<dim3(16, 64, 2), 256, 0, stream>>>(
        Mean32, Sec32, content, cmean, cinv, Op_hi);

    // ---- out conv (2-term, np=3: (Whi+Wlo)*O_hi): bias + residual(content) -> d_out ----
    {
        ZTab tf = {};
        for (int z = 0; z < 2; ++z) {
            tf.ooff[z] = (long)z * KN;
            tf.boff[z] = (long)z * KN;
            tf.np[z]   = 3;
            tf.bias[z] = out_b;
        }
        gemm_split<3, true, false><<<dim3(32, 4, 2), 256, 0, stream>>>(
            Wh[3], Wh[3] + CHCH, Op_hi, nullptr, content,
            out, nullptr, nullptr, nullptr, CH, NS, CH, tf);
    }
}